// Round 1
// baseline (131.699 us; speedup 1.0000x reference)
//
#include <hip/hip_runtime.h>

// out[b,o,n] = sum_{k,c} input[b,c,n] * weight[o,k,c] * score[b,k,n]
// B=8, C_IN=16, C_OUT=16, K=4, N=524288. All fp32. Memory-bound (576 MB traffic).

constexpr int B     = 8;
constexpr int C_IN  = 16;
constexpr int C_OUT = 16;
constexpr int KK    = 4;
constexpr int N     = 524288;
constexpr int N4    = N / 4;   // float4 elements per (b, channel) row

__global__ __launch_bounds__(256) void
TransformConv1d_39264591020709_kernel(const float* __restrict__ in,
                                      const float* __restrict__ w,
                                      const float* __restrict__ sc,
                                      float* __restrict__ out) {
    const int idx = blockIdx.x * blockDim.x + threadIdx.x;   // 0 .. B*N4-1
    const int b  = idx >> 17;        // idx / N4  (N4 = 131072 = 2^17)
    const int n4 = idx & (N4 - 1);   // idx % N4

    const float4* inB  = reinterpret_cast<const float4*>(in)  + (size_t)b * C_IN * N4;
    const float4* scB  = reinterpret_cast<const float4*>(sc)  + (size_t)b * KK   * N4;
    float4*       outB = reinterpret_cast<float4*>(out)       + (size_t)b * C_OUT * N4;

    // Load this thread's 4-wide slice of all input channels and scores.
    float4 x[C_IN];
#pragma unroll
    for (int c = 0; c < C_IN; ++c) x[c] = inB[c * N4 + n4];

    float4 a[KK];
#pragma unroll
    for (int k = 0; k < KK; ++k) a[k] = scB[k * N4 + n4];

#pragma unroll
    for (int o = 0; o < C_OUT; ++o) {
        float4 acc = make_float4(0.f, 0.f, 0.f, 0.f);
#pragma unroll
        for (int k = 0; k < KK; ++k) {
            float4 p = make_float4(0.f, 0.f, 0.f, 0.f);
#pragma unroll
            for (int c = 0; c < C_IN; ++c) {
                const float wv = w[(o * KK + k) * C_IN + c];  // uniform -> s_load
                p.x = fmaf(wv, x[c].x, p.x);
                p.y = fmaf(wv, x[c].y, p.y);
                p.z = fmaf(wv, x[c].z, p.z);
                p.w = fmaf(wv, x[c].w, p.w);
            }
            acc.x = fmaf(a[k].x, p.x, acc.x);
            acc.y = fmaf(a[k].y, p.y, acc.y);
            acc.z = fmaf(a[k].z, p.z, acc.z);
            acc.w = fmaf(a[k].w, p.w, acc.w);
        }
        outB[o * N4 + n4] = acc;
    }
}

extern "C" void kernel_launch(void* const* d_in, const int* in_sizes, int n_in,
                              void* d_out, int out_size, void* d_ws, size_t ws_size,
                              hipStream_t stream) {
    const float* in = (const float*)d_in[0];   // (B, C_IN, N)
    const float* w  = (const float*)d_in[1];   // (C_OUT, K, C_IN)
    const float* sc = (const float*)d_in[2];   // (B, K, N)
    float* out = (float*)d_out;                // (B, C_OUT, N)

    const int total_threads = B * N4;          // 1,048,576
    const int block = 256;
    const int grid  = total_threads / block;   // 4096
    TransformConv1d_39264591020709_kernel<<<grid, block, 0, stream>>>(in, w, sc, out);
}

// Round 3
// 123.214 us; speedup vs baseline: 1.0689x; 1.0689x over previous
//
#include <hip/hip_runtime.h>

// out[b,o,n] = sum_{k,c} input[b,c,n] * weight[o,k,c] * score[b,k,n]
// B=8, C_IN=16, C_OUT=16, K=4, N=524288. All fp32.
// Compute floor ~58us (9.1 GFLOP @ 157 TF), HBM floor ~67us (420 MB @ 6.3 TB/s).
// Round 1 lesson: default launch_bounds squeezed VGPR to 64 -> compiler re-read
// x[] from L1 per o-iteration (L1 BW-bound). Allow 3 waves/EU -> ~168 VGPR cap
// so the 64-reg x[] slice stays resident.

constexpr int B     = 8;
constexpr int C_IN  = 16;
constexpr int C_OUT = 16;
constexpr int KK    = 4;
constexpr int N     = 524288;
constexpr int N4    = N / 4;   // float4 elements per (b, channel) row

typedef float vfloat4 __attribute__((ext_vector_type(4)));  // native vector for nt-store

__global__ __launch_bounds__(256, 3) void
TransformConv1d_39264591020709_kernel(const float* __restrict__ in,
                                      const float* __restrict__ w,
                                      const float* __restrict__ sc,
                                      float* __restrict__ out) {
    const int idx = blockIdx.x * blockDim.x + threadIdx.x;   // 0 .. B*N4-1
    const int b  = idx >> 17;        // idx / N4  (N4 = 131072 = 2^17)
    const int n4 = idx & (N4 - 1);   // idx % N4

    const float4* inB  = reinterpret_cast<const float4*>(in)  + (size_t)b * C_IN * N4;
    const float4* scB  = reinterpret_cast<const float4*>(sc)  + (size_t)b * KK   * N4;
    float4*       outB = reinterpret_cast<float4*>(out)       + (size_t)b * C_OUT * N4;

    // Load this thread's 4-wide slice of all input channels and scores.
    // These MUST stay register-resident (64+16 VGPRs) -> launch_bounds(256,3).
    float4 x[C_IN];
#pragma unroll
    for (int c = 0; c < C_IN; ++c) x[c] = inB[c * N4 + n4];

    float4 a[KK];
#pragma unroll
    for (int k = 0; k < KK; ++k) a[k] = scB[k * N4 + n4];

#pragma unroll
    for (int o = 0; o < C_OUT; ++o) {
        float4 acc = make_float4(0.f, 0.f, 0.f, 0.f);
#pragma unroll
        for (int k = 0; k < KK; ++k) {
            float4 p = make_float4(0.f, 0.f, 0.f, 0.f);
#pragma unroll
            for (int c = 0; c < C_IN; ++c) {
                const float wv = w[(o * KK + k) * C_IN + c];  // uniform -> s_load via K$
                p.x = fmaf(wv, x[c].x, p.x);
                p.y = fmaf(wv, x[c].y, p.y);
                p.z = fmaf(wv, x[c].z, p.z);
                p.w = fmaf(wv, x[c].w, p.w);
            }
            acc.x = fmaf(a[k].x, p.x, acc.x);
            acc.y = fmaf(a[k].y, p.y, acc.y);
            acc.z = fmaf(a[k].z, p.z, acc.z);
            acc.w = fmaf(a[k].w, p.w, acc.w);
        }
        // Output is write-once/streamed: non-temporal keeps input resident in L2/L3.
        vfloat4 v = { acc.x, acc.y, acc.z, acc.w };
        __builtin_nontemporal_store(v, reinterpret_cast<vfloat4*>(&outB[o * N4 + n4]));
    }
}

extern "C" void kernel_launch(void* const* d_in, const int* in_sizes, int n_in,
                              void* d_out, int out_size, void* d_ws, size_t ws_size,
                              hipStream_t stream) {
    const float* in = (const float*)d_in[0];   // (B, C_IN, N)
    const float* w  = (const float*)d_in[1];   // (C_OUT, K, C_IN)
    const float* sc = (const float*)d_in[2];   // (B, K, N)
    float* out = (float*)d_out;                // (B, C_OUT, N)

    const int total_threads = B * N4;          // 1,048,576
    const int block = 256;
    const int grid  = total_threads / block;   // 4096
    TransformConv1d_39264591020709_kernel<<<grid, block, 0, stream>>>(in, w, sc, out);
}